// Round 1
// baseline (136.468 us; speedup 1.0000x reference)
//
#include <hip/hip_runtime.h>
#include <hip/hip_bf16.h>

#define NROWS 8192
#define DIM 512
#define BM 128
#define BN 128
#define BK 64

typedef __bf16 bf16x8 __attribute__((ext_vector_type(8)));
typedef unsigned short u16x8 __attribute__((ext_vector_type(8)));
typedef float f32x4 __attribute__((ext_vector_type(4)));

__device__ __forceinline__ unsigned short f2bf(float f) {
  unsigned int u = __float_as_uint(f);
  u += 0x7fffu + ((u >> 16) & 1u);
  return (unsigned short)(u >> 16);
}

__device__ __forceinline__ void gld_lds16(const void* g, void* l) {
  __builtin_amdgcn_global_load_lds(
      (__attribute__((address_space(1))) unsigned int*)(g),
      (__attribute__((address_space(3))) unsigned int*)(l),
      16, 0, 0);
}

// ---------- Phase 1: normalize rows -> bf16; diag logits in fp32 ----------
__global__ __launch_bounds__(128) void prep_k(
    const float* __restrict__ q, const float* __restrict__ p,
    unsigned short* __restrict__ qh, unsigned short* __restrict__ ph,
    float* __restrict__ diag) {
  const int i = blockIdx.x;
  const int t = threadIdx.x;
  const int lane = t & 63, wid = t >> 6;
  const float4 qv = ((const float4*)(q + (size_t)i * DIM))[t];
  const float4 pv = ((const float4*)(p + (size_t)i * DIM))[t];
  float ssq = qv.x*qv.x + qv.y*qv.y + qv.z*qv.z + qv.w*qv.w;
  float ssp = pv.x*pv.x + pv.y*pv.y + pv.z*pv.z + pv.w*pv.w;
  float dt  = qv.x*pv.x + qv.y*pv.y + qv.z*pv.z + qv.w*pv.w;
  #pragma unroll
  for (int m = 1; m < 64; m <<= 1) {
    ssq += __shfl_xor(ssq, m, 64);
    ssp += __shfl_xor(ssp, m, 64);
    dt  += __shfl_xor(dt,  m, 64);
  }
  __shared__ float red[3][2];
  if (lane == 0) { red[0][wid] = ssq; red[1][wid] = ssp; red[2][wid] = dt; }
  __syncthreads();
  ssq = red[0][0] + red[0][1];
  ssp = red[1][0] + red[1][1];
  dt  = red[2][0] + red[2][1];
  const float invq = 1.0f / fmaxf(sqrtf(ssq), 1e-8f);
  const float invp = 1.0f / fmaxf(sqrtf(ssp), 1e-8f);
  ushort4 qo, po;
  qo.x = f2bf(qv.x * invq); qo.y = f2bf(qv.y * invq);
  qo.z = f2bf(qv.z * invq); qo.w = f2bf(qv.w * invq);
  po.x = f2bf(pv.x * invp); po.y = f2bf(pv.y * invp);
  po.z = f2bf(pv.z * invp); po.w = f2bf(pv.w * invp);
  ((ushort4*)(qh + (size_t)i * DIM))[t] = qo;
  ((ushort4*)(ph + (size_t)i * DIM))[t] = po;
  if (t == 0) diag[i] = dt * invq * invp * 20.0f;
}

// ---------- Phase 2: C = qn @ pn^T, fused exp(sim-20) row-sum ----------
// m97 structure: 128x128 tile, BK=64, 4 waves (2x2 of 64x64), global_load_lds.
__global__ __launch_bounds__(256) void gemm_lse_k(
    const unsigned short* __restrict__ qh, const unsigned short* __restrict__ ph,
    float* __restrict__ partial) {
  __shared__ __attribute__((aligned(16))) unsigned short As[BM * BK];
  __shared__ __attribute__((aligned(16))) unsigned short Bs[BN * BK];
  __shared__ float psum[2][BM];
  const int tid = threadIdx.x;
  const int lane = tid & 63, wid = tid >> 6;
  const int wr = wid >> 1, wc = wid & 1;
  const int bm = blockIdx.y * BM, bn = blockIdx.x * BN;
  const int l15 = lane & 15, l4 = lane >> 4;
  f32x4 acc[4][4] = {};

  for (int kt = 0; kt < DIM / BK; ++kt) {
    const int k0 = kt * BK;
    __syncthreads();
    #pragma unroll
    for (int i = 0; i < 4; ++i) {
      const int s = i * 256 + tid;
      const int row = s >> 3, ce = (s & 7) * 8;  // 8 bf16 = 16B per slot
      char* dA = (char*)As + (i * 256 + wid * 64) * 16;  // wave-uniform dest
      char* dB = (char*)Bs + (i * 256 + wid * 64) * 16;
      gld_lds16(qh + (size_t)(bm + row) * DIM + k0 + ce, dA);
      gld_lds16(ph + (size_t)(bn + row) * DIM + k0 + ce, dB);
    }
    __syncthreads();
    #pragma unroll
    for (int ks = 0; ks < 2; ++ks) {
      bf16x8 a[4], b[4];
      #pragma unroll
      for (int mf = 0; mf < 4; ++mf)
        a[mf] = __builtin_bit_cast(bf16x8,
            *(const u16x8*)(As + (wr * 64 + mf * 16 + l15) * BK + ks * 32 + l4 * 8));
      #pragma unroll
      for (int nf = 0; nf < 4; ++nf)
        b[nf] = __builtin_bit_cast(bf16x8,
            *(const u16x8*)(Bs + (wc * 64 + nf * 16 + l15) * BK + ks * 32 + l4 * 8));
      #pragma unroll
      for (int mf = 0; mf < 4; ++mf)
        #pragma unroll
        for (int nf = 0; nf < 4; ++nf)
          acc[mf][nf] = __builtin_amdgcn_mfma_f32_16x16x32_bf16(a[mf], b[nf], acc[mf][nf], 0, 0, 0);
    }
  }

  // Epilogue: e = exp(cos*20 - 20); per-row sums over this block's 128 cols.
  // C/D layout: col = lane&15, row = (lane>>4)*4 + reg  [m89 verified]
  float rs[4][4];
  #pragma unroll
  for (int mf = 0; mf < 4; ++mf) {
    #pragma unroll
    for (int r = 0; r < 4; ++r) {
      float s = 0.0f;
      #pragma unroll
      for (int nf = 0; nf < 4; ++nf)
        s += __expf(acc[mf][nf][r] * 20.0f - 20.0f);
      // reduce across 16 cols (lanes sharing l>>4 group)
      s += __shfl_xor(s, 1, 64);
      s += __shfl_xor(s, 2, 64);
      s += __shfl_xor(s, 4, 64);
      s += __shfl_xor(s, 8, 64);
      rs[mf][r] = s;
    }
  }
  if (l15 == 0) {
    #pragma unroll
    for (int mf = 0; mf < 4; ++mf)
      #pragma unroll
      for (int r = 0; r < 4; ++r)
        psum[wc][wr * 64 + mf * 16 + l4 * 4 + r] = rs[mf][r];
  }
  __syncthreads();
  if (tid < BM)
    partial[(size_t)(bm + tid) * 64 + blockIdx.x] = psum[0][tid] + psum[1][tid];
}

// ---------- Phase 3a: per-row loss ----------
__global__ __launch_bounds__(256) void rowloss_k(
    const float* __restrict__ partial, const float* __restrict__ diag,
    float* __restrict__ rowloss) {
  const int i = blockIdx.x * 256 + threadIdx.x;
  const float* pr = partial + (size_t)i * 64;
  float s = 0.0f;
  #pragma unroll
  for (int c = 0; c < 64; ++c) s += pr[c];
  rowloss[i] = __logf(s) + 20.0f - diag[i];
}

// ---------- Phase 3b: mean ----------
__global__ __launch_bounds__(256) void final_k(
    const float* __restrict__ rowloss, float* __restrict__ out) {
  const int t = threadIdx.x;
  float s = 0.0f;
  for (int j = t; j < NROWS; j += 256) s += rowloss[j];
  #pragma unroll
  for (int m = 1; m < 64; m <<= 1) s += __shfl_xor(s, m, 64);
  __shared__ float red[4];
  if ((t & 63) == 0) red[t >> 6] = s;
  __syncthreads();
  if (t == 0) out[0] = (red[0] + red[1] + red[2] + red[3]) * (1.0f / (float)NROWS);
}

extern "C" void kernel_launch(void* const* d_in, const int* in_sizes, int n_in,
                              void* d_out, int out_size, void* d_ws, size_t ws_size,
                              hipStream_t stream) {
  const float* q = (const float*)d_in[0];
  const float* p = (const float*)d_in[1];
  char* w = (char*)d_ws;
  unsigned short* qh = (unsigned short*)w;                    // 8 MB
  unsigned short* ph = (unsigned short*)(w + 8388608);        // 8 MB
  float* partial    = (float*)(w + 16777216);                 // 2 MB  [8192][64]
  float* diag       = (float*)(w + 18874368);                 // 32 KB
  float* rowloss    = (float*)(w + 18874368 + 32768);         // 32 KB
  float* out = (float*)d_out;

  prep_k<<<NROWS, 128, 0, stream>>>(q, p, qh, ph, diag);
  gemm_lse_k<<<dim3(64, 64), 256, 0, stream>>>(qh, ph, partial);
  rowloss_k<<<NROWS / 256, 256, 0, stream>>>(partial, diag, rowloss);
  final_k<<<1, 256, 0, stream>>>(rowloss, out);
}

// Round 3
// 115.678 us; speedup vs baseline: 1.1797x; 1.1797x over previous
//
#include <hip/hip_runtime.h>
#include <hip/hip_bf16.h>

#define NROWS 8192
#define DIM 512
#define BM 256
#define BN 256
#define BK 64

typedef __bf16 bf16x8 __attribute__((ext_vector_type(8)));
typedef unsigned short u16x8 __attribute__((ext_vector_type(8)));
typedef float f32x4 __attribute__((ext_vector_type(4)));

__device__ __forceinline__ unsigned short f2bf(float f) {
  unsigned int u = __float_as_uint(f);
  u += 0x7fffu + ((u >> 16) & 1u);
  return (unsigned short)(u >> 16);
}

__device__ __forceinline__ void gld_lds16(const void* g, void* l) {
  __builtin_amdgcn_global_load_lds(
      (__attribute__((address_space(1))) unsigned int*)(g),
      (__attribute__((address_space(3))) unsigned int*)(l),
      16, 0, 0);
}

// ---------- Phase 1: normalize rows -> bf16; diag logits in fp32 ----------
__global__ __launch_bounds__(128) void prep_k(
    const float* __restrict__ q, const float* __restrict__ p,
    unsigned short* __restrict__ qh, unsigned short* __restrict__ ph,
    float* __restrict__ diag) {
  const int i = blockIdx.x;
  const int t = threadIdx.x;
  const int lane = t & 63, wid = t >> 6;
  const float4 qv = ((const float4*)(q + (size_t)i * DIM))[t];
  const float4 pv = ((const float4*)(p + (size_t)i * DIM))[t];
  float ssq = qv.x*qv.x + qv.y*qv.y + qv.z*qv.z + qv.w*qv.w;
  float ssp = pv.x*pv.x + pv.y*pv.y + pv.z*pv.z + pv.w*pv.w;
  float dt  = qv.x*pv.x + qv.y*pv.y + qv.z*pv.z + qv.w*pv.w;
  #pragma unroll
  for (int m = 1; m < 64; m <<= 1) {
    ssq += __shfl_xor(ssq, m, 64);
    ssp += __shfl_xor(ssp, m, 64);
    dt  += __shfl_xor(dt,  m, 64);
  }
  __shared__ float red[3][2];
  if (lane == 0) { red[0][wid] = ssq; red[1][wid] = ssp; red[2][wid] = dt; }
  __syncthreads();
  ssq = red[0][0] + red[0][1];
  ssp = red[1][0] + red[1][1];
  dt  = red[2][0] + red[2][1];
  const float invq = 1.0f / fmaxf(sqrtf(ssq), 1e-8f);
  const float invp = 1.0f / fmaxf(sqrtf(ssp), 1e-8f);
  ushort4 qo, po;
  qo.x = f2bf(qv.x * invq); qo.y = f2bf(qv.y * invq);
  qo.z = f2bf(qv.z * invq); qo.w = f2bf(qv.w * invq);
  po.x = f2bf(pv.x * invp); po.y = f2bf(pv.y * invp);
  po.z = f2bf(pv.z * invp); po.w = f2bf(pv.w * invp);
  ((ushort4*)(qh + (size_t)i * DIM))[t] = qo;
  ((ushort4*)(ph + (size_t)i * DIM))[t] = po;
  if (t == 0) diag[i] = dt * invq * invp * 20.0f;
}

// ---------- Phase 2: 256x256-tile GEMM, swizzled LDS, deep prefetch ----------
// 512 threads = 8 waves (2 Mx4 N). Per wave: 128x64 output = acc[8][4] f32x4.
// LDS: 2 x 64KB K-tile buffers (A 32KB + B 32KB each), T2 XOR-swizzled.
// Staging for K-tile kt+1 fully issued at top of kt's compute (race-free:
// writes target the idle buffer; ~1200cy issue-to-use hides HBM latency, so
// the boundary __syncthreads' vmcnt(0) is nearly free).
__device__ __forceinline__ void stage_tile(
    const char* __restrict__ qh8, const char* __restrict__ ph8,
    char* buf, int bm, int bn, int kb, int tid) {
  #pragma unroll
  for (int j = 0; j < 4; ++j) {
    const int idx = j * 512 + tid;
    const int row = idx >> 3;
    const int cb  = (tid & 7) << 4;
    const int scb = cb ^ ((row & 7) << 4);   // pre-swizzled source (rule #21)
    gld_lds16(qh8 + (size_t)(bm + row) * 1024 + kb + scb, buf + idx * 16);
    gld_lds16(ph8 + (size_t)(bn + row) * 1024 + kb + scb, buf + 32768 + idx * 16);
  }
}

__global__ __launch_bounds__(512, 2) void gemm_lse_k(
    const unsigned short* __restrict__ qh, const unsigned short* __restrict__ ph,
    float* __restrict__ partial) {
  __shared__ __attribute__((aligned(16))) char lds[131072];
  const int tid = threadIdx.x;
  const int lane = tid & 63, wid = tid >> 6;
  const int wr = wid >> 2, wc = wid & 3;         // 2 x 4 wave grid
  const int l15 = lane & 15, l4 = lane >> 4;
  // XCD-aware swizzle (1024 blocks, 1024 % 8 == 0 -> simple form valid)
  const int b = blockIdx.x;
  const int swz = (b & 7) * 128 + (b >> 3);
  const int by = swz >> 5, bx = swz & 31;
  const int bm = by * BM, bn = bx * BN;
  const char* qh8 = (const char*)qh;
  const char* ph8 = (const char*)ph;

  f32x4 acc[8][4] = {};
  char* cur = lds;
  char* nxt = lds + 65536;

  stage_tile(qh8, ph8, cur, bm, bn, 0, tid);
  __syncthreads();

  for (int kt = 0; kt < DIM / BK; ++kt) {
    if (kt < DIM / BK - 1)
      stage_tile(qh8, ph8, nxt, bm, bn, (kt + 1) * 128, tid);
    #pragma unroll
    for (int qm = 0; qm < 2; ++qm) {
      #pragma unroll
      for (int qn = 0; qn < 2; ++qn) {
        bf16x8 af[2][4], bfr[2][2];
        #pragma unroll
        for (int ks = 0; ks < 2; ++ks) {
          const int cb = (ks * 64 + (l4 << 4)) ^ ((l15 & 7) << 4);  // T2 swizzle
          #pragma unroll
          for (int mf = 0; mf < 4; ++mf) {
            const int r = wr * 128 + qm * 64 + mf * 16 + l15;
            af[ks][mf] = __builtin_bit_cast(bf16x8,
                *(const u16x8*)(cur + r * 128 + cb));
          }
          #pragma unroll
          for (int nf = 0; nf < 2; ++nf) {
            const int r = wc * 64 + qn * 32 + nf * 16 + l15;
            bfr[ks][nf] = __builtin_bit_cast(bf16x8,
                *(const u16x8*)(cur + 32768 + r * 128 + cb));
          }
        }
        __builtin_amdgcn_s_setprio(1);
        #pragma unroll
        for (int mf = 0; mf < 4; ++mf)
          #pragma unroll
          for (int nf = 0; nf < 2; ++nf)
            #pragma unroll
            for (int ks = 0; ks < 2; ++ks)
              acc[qm * 4 + mf][qn * 2 + nf] = __builtin_amdgcn_mfma_f32_16x16x32_bf16(
                  af[ks][mf], bfr[ks][nf], acc[qm * 4 + mf][qn * 2 + nf], 0, 0, 0);
        __builtin_amdgcn_s_setprio(0);
      }
    }
    __syncthreads();          // vmcnt(0)+lgkmcnt(0)+barrier: next tile landed
    char* t2 = cur; cur = nxt; nxt = t2;
  }

  // Epilogue: exp(cos*20 - 20), row-sum over this block's 256 cols.
  // C/D layout: col = l15, row-in-frag = l4*4 + r   [m89 verified]
  float* psum = (float*)lds;  // [4][256] overlay on buf0-A (kt=7 read buf1)
  #pragma unroll
  for (int am = 0; am < 8; ++am) {
    #pragma unroll
    for (int r = 0; r < 4; ++r) {
      float s = 0.0f;
      #pragma unroll
      for (int nb = 0; nb < 4; ++nb)
        s += __expf(acc[am][nb][r] * 20.0f - 20.0f);
      s += __shfl_xor(s, 1, 64);
      s += __shfl_xor(s, 2, 64);
      s += __shfl_xor(s, 4, 64);
      s += __shfl_xor(s, 8, 64);
      if (l15 == 0)
        psum[wc * 256 + wr * 128 + am * 16 + l4 * 4 + r] = s;
    }
  }
  __syncthreads();
  if (tid < 256) {
    float s = psum[tid] + psum[256 + tid] + psum[512 + tid] + psum[768 + tid];
    partial[(size_t)(bm + tid) * 32 + bx] = s;
  }
}

// ---------- Phase 3a: per-row loss ----------
__global__ __launch_bounds__(256) void rowloss_k(
    const float* __restrict__ partial, const float* __restrict__ diag,
    float* __restrict__ rowloss) {
  const int i = blockIdx.x * 256 + threadIdx.x;
  const float4* pr = (const float4*)(partial + (size_t)i * 32);
  float s = 0.0f;
  #pragma unroll
  for (int c = 0; c < 8; ++c) {
    const float4 v = pr[c];
    s += v.x + v.y + v.z + v.w;
  }
  rowloss[i] = __logf(s) + 20.0f - diag[i];
}

// ---------- Phase 3b: mean ----------
__global__ __launch_bounds__(256) void final_k(
    const float* __restrict__ rowloss, float* __restrict__ out) {
  const int t = threadIdx.x;
  float s = 0.0f;
  for (int j = t; j < NROWS; j += 256) s += rowloss[j];
  #pragma unroll
  for (int m = 1; m < 64; m <<= 1) s += __shfl_xor(s, m, 64);
  __shared__ float red[4];
  if ((t & 63) == 0) red[t >> 6] = s;
  __syncthreads();
  if (t == 0) out[0] = (red[0] + red[1] + red[2] + red[3]) * (1.0f / (float)NROWS);
}

extern "C" void kernel_launch(void* const* d_in, const int* in_sizes, int n_in,
                              void* d_out, int out_size, void* d_ws, size_t ws_size,
                              hipStream_t stream) {
  const float* q = (const float*)d_in[0];
  const float* p = (const float*)d_in[1];
  char* w = (char*)d_ws;
  unsigned short* qh = (unsigned short*)w;                    // 8 MB
  unsigned short* ph = (unsigned short*)(w + 8388608);        // 8 MB
  float* partial    = (float*)(w + 16777216);                 // 1 MB [8192][32]
  float* diag       = (float*)(w + 17825792);                 // 32 KB
  float* rowloss    = (float*)(w + 17858560);                 // 32 KB
  float* out = (float*)d_out;

  prep_k<<<NROWS, 128, 0, stream>>>(q, p, qh, ph, diag);
  gemm_lse_k<<<1024, 512, 0, stream>>>(qh, ph, partial);
  rowloss_k<<<NROWS / 256, 256, 0, stream>>>(partial, diag, rowloss);
  final_k<<<1, 256, 0, stream>>>(rowloss, out);
}

// Round 5
// 106.373 us; speedup vs baseline: 1.2829x; 1.0875x over previous
//
#include <hip/hip_runtime.h>
#include <hip/hip_bf16.h>

#define NROWS 8192
#define DIM 512
#define BM 256
#define BN 256

typedef __bf16 bf16x8 __attribute__((ext_vector_type(8)));
typedef unsigned short u16x8 __attribute__((ext_vector_type(8)));
typedef float f32x4 __attribute__((ext_vector_type(4)));

__device__ __forceinline__ unsigned short f2bf(float f) {
  unsigned int u = __float_as_uint(f);
  u += 0x7fffu + ((u >> 16) & 1u);
  return (unsigned short)(u >> 16);
}

__device__ __forceinline__ void gld_lds16(const void* g, void* l) {
  __builtin_amdgcn_global_load_lds(
      (__attribute__((address_space(1))) unsigned int*)(g),
      (__attribute__((address_space(3))) unsigned int*)(l),
      16, 0, 0);
}

// ---------- Phase 1: normalize rows -> bf16; diag logits in fp32 ----------
__global__ __launch_bounds__(128) void prep_k(
    const float* __restrict__ q, const float* __restrict__ p,
    unsigned short* __restrict__ qh, unsigned short* __restrict__ ph,
    float* __restrict__ diag) {
  const int i = blockIdx.x;
  const int t = threadIdx.x;
  const int lane = t & 63, wid = t >> 6;
  const float4 qv = ((const float4*)(q + (size_t)i * DIM))[t];
  const float4 pv = ((const float4*)(p + (size_t)i * DIM))[t];
  float ssq = qv.x*qv.x + qv.y*qv.y + qv.z*qv.z + qv.w*qv.w;
  float ssp = pv.x*pv.x + pv.y*pv.y + pv.z*pv.z + pv.w*pv.w;
  float dt  = qv.x*pv.x + qv.y*pv.y + qv.z*pv.z + qv.w*pv.w;
  #pragma unroll
  for (int m = 1; m < 64; m <<= 1) {
    ssq += __shfl_xor(ssq, m, 64);
    ssp += __shfl_xor(ssp, m, 64);
    dt  += __shfl_xor(dt,  m, 64);
  }
  __shared__ float red[3][2];
  if (lane == 0) { red[0][wid] = ssq; red[1][wid] = ssp; red[2][wid] = dt; }
  __syncthreads();
  ssq = red[0][0] + red[0][1];
  ssp = red[1][0] + red[1][1];
  dt  = red[2][0] + red[2][1];
  const float invq = 1.0f / fmaxf(sqrtf(ssq), 1e-8f);
  const float invp = 1.0f / fmaxf(sqrtf(ssp), 1e-8f);
  ushort4 qo, po;
  qo.x = f2bf(qv.x * invq); qo.y = f2bf(qv.y * invq);
  qo.z = f2bf(qv.z * invq); qo.w = f2bf(qv.w * invq);
  po.x = f2bf(pv.x * invp); po.y = f2bf(pv.y * invp);
  po.z = f2bf(pv.z * invp); po.w = f2bf(pv.w * invp);
  ((ushort4*)(qh + (size_t)i * DIM))[t] = qo;
  ((ushort4*)(ph + (size_t)i * DIM))[t] = po;
  if (t == 0) diag[i] = dt * invq * invp * 20.0f;
}

// ---------- Phase 2: 256x256 GEMM, 4-phase/K-tile pipelined schedule ----------
// 8 waves (2M x 4N), per-wave 128x64 out. LDS 2 x (A 32KB + B 32KB), XOR-swz.
// Per phase: {ds_read quad frags; stage 1 half-tile (2 gld_lds); vmcnt(4);
//   barrier; lgkmcnt(0)+sched_barrier; setprio(1) 16 MFMA setprio(0); barrier}.
// Stage order A0,B0,B1,A1 + zigzag quad order (0,0)(0,1)(1,1)(1,0): every half
// is drained by a counted vmcnt >=1 phase before its first ds_read.
// Last K-tile peeled with explicit vmcnt(2)/vmcnt(0) drains (no staging there,
// so the in-loop vmcnt(4) would never retire the final two halves).
__device__ __forceinline__ void read_af(bf16x8 af[2][4], const char* rb,
                                        int qm, int rowAoff, int l4swz) {
  #pragma unroll
  for (int ks = 0; ks < 2; ++ks)
    #pragma unroll
    for (int mf = 0; mf < 4; ++mf)
      af[ks][mf] = __builtin_bit_cast(bf16x8,
          *(const u16x8*)(rb + qm * 16384 + rowAoff + mf * 2048 + (l4swz ^ (ks * 64))));
}
__device__ __forceinline__ void read_bf(bf16x8 bfr[2][2], const char* rb,
                                        int qn, int rowBoff, int l4swz) {
  #pragma unroll
  for (int ks = 0; ks < 2; ++ks)
    #pragma unroll
    for (int nf = 0; nf < 2; ++nf)
      bfr[ks][nf] = __builtin_bit_cast(bf16x8,
          *(const u16x8*)(rb + 32768 + qn * 16384 + rowBoff + nf * 2048 + (l4swz ^ (ks * 64))));
}
// stage one 128-row half of one operand (2 x gld_lds per thread)
__device__ __forceinline__ void stage_half(const char* __restrict__ g, char* dstb,
                                           int rowbase, int h, int tid, int kb) {
  #pragma unroll
  for (int j = 0; j < 2; ++j) {
    const int idx = j * 512 + tid;
    const int rl = idx >> 3;
    const int scb = ((idx & 7) << 4) ^ ((rl & 7) << 4);
    gld_lds16(g + (size_t)(rowbase + h * 128 + rl) * 1024 + kb + scb,
              dstb + h * 16384 + idx * 16);
  }
}

#define MFMA_QUAD(QM, QN)                                                     \
  __builtin_amdgcn_s_setprio(1);                                              \
  _Pragma("unroll") for (int mf = 0; mf < 4; ++mf)                            \
    _Pragma("unroll") for (int nf = 0; nf < 2; ++nf)                          \
      _Pragma("unroll") for (int ks = 0; ks < 2; ++ks)                        \
        acc[QM * 4 + mf][QN * 2 + nf] =                                       \
            __builtin_amdgcn_mfma_f32_16x16x32_bf16(                          \
                af[ks][mf], bfr[ks][nf], acc[QM * 4 + mf][QN * 2 + nf], 0, 0, 0); \
  __builtin_amdgcn_s_setprio(0);

#define PHASE_SYNC()                                                          \
  asm volatile("s_waitcnt vmcnt(4)" ::: "memory");                            \
  __builtin_amdgcn_s_barrier();                                               \
  asm volatile("s_waitcnt lgkmcnt(0)" ::: "memory");                          \
  __builtin_amdgcn_sched_barrier(0);

#define LGKM_SYNC()                                                           \
  asm volatile("s_waitcnt lgkmcnt(0)" ::: "memory");                          \
  __builtin_amdgcn_sched_barrier(0);

__global__ __launch_bounds__(512, 2) void gemm_lse_k(
    const unsigned short* __restrict__ qh, const unsigned short* __restrict__ ph,
    float* __restrict__ partial) {
  __shared__ __attribute__((aligned(16))) char lds[131072];
  const int tid = threadIdx.x;
  const int lane = tid & 63, wid = tid >> 6;
  const int wr = wid >> 2, wc = wid & 3;
  const int l15 = lane & 15, l4 = lane >> 4;
  const int rowAoff = (wr * 64 + l15) * 128;
  const int rowBoff = (wc * 32 + l15) * 128;
  const int l4swz = (l4 << 4) ^ ((l15 & 7) << 4);
  // XCD remap: 8x16 rectangle per XCD (bijective; 1024 = 32x32 grid)
  const int b = blockIdx.x;
  const int x = b & 7, local = b >> 3;
  const int by = (x >> 1) * 8 + (local >> 4);
  const int bx = (x & 1) * 16 + (local & 15);
  const int bm = by * BM, bn = bx * BN;
  const char* qh8 = (const char*)qh;
  const char* ph8 = (const char*)ph;

  f32x4 acc[8][4] = {};
  bf16x8 af[2][4], bfr[2][2];

  // Prologue: stage tile 0 fully, drain, barrier.
  stage_half(qh8, lds, bm, 0, tid, 0);
  stage_half(ph8, lds + 32768, bn, 0, tid, 0);
  stage_half(ph8, lds + 32768, bn, 1, tid, 0);
  stage_half(qh8, lds, bm, 1, tid, 0);
  asm volatile("s_waitcnt vmcnt(0)" ::: "memory");
  __builtin_amdgcn_s_barrier();

  #pragma unroll 2
  for (int t = 0; t < 7; ++t) {
    const char* rb = lds + (t & 1) * 65536;
    char* sbA = lds + ((t + 1) & 1) * 65536;
    char* sbB = sbA + 32768;
    const int kbn = (t + 1) * 128;
    // phase 0: quad (0,0)
    read_af(af, rb, 0, rowAoff, l4swz);
    read_bf(bfr, rb, 0, rowBoff, l4swz);
    stage_half(qh8, sbA, bm, 0, tid, kbn);   // A half0 of t+1
    PHASE_SYNC();
    MFMA_QUAD(0, 0);
    __builtin_amdgcn_s_barrier();
    // phase 1: quad (0,1)  (af reused)
    read_bf(bfr, rb, 1, rowBoff, l4swz);
    stage_half(ph8, sbB, bn, 0, tid, kbn);   // B half0
    PHASE_SYNC();
    MFMA_QUAD(0, 1);
    __builtin_amdgcn_s_barrier();
    // phase 2: quad (1,1)  (bfr reused)
    read_af(af, rb, 1, rowAoff, l4swz);
    stage_half(ph8, sbB, bn, 1, tid, kbn);   // B half1
    PHASE_SYNC();
    MFMA_QUAD(1, 1);
    __builtin_amdgcn_s_barrier();
    // phase 3: quad (1,0)  (af reused)
    read_bf(bfr, rb, 0, rowBoff, l4swz);
    stage_half(qh8, sbA, bm, 1, tid, kbn);   // A half1
    PHASE_SYNC();
    MFMA_QUAD(1, 0);
    __builtin_amdgcn_s_barrier();
  }

  // ---- Peeled last K-tile (t=7, reads buf1, no staging): explicit drains ----
  {
    const char* rb = lds + 65536;
    // p0: quad (0,0). Queue = [B1(t6p2) x2, A1(t6p3) x2].
    read_af(af, rb, 0, rowAoff, l4swz);
    read_bf(bfr, rb, 0, rowBoff, l4swz);
    asm volatile("s_waitcnt vmcnt(2)" ::: "memory");   // drains B half1
    __builtin_amdgcn_s_barrier();
    LGKM_SYNC();
    MFMA_QUAD(0, 0);
    __builtin_amdgcn_s_barrier();
    // p1: quad (0,1) — reads B half1 (drained above)
    read_bf(bfr, rb, 1, rowBoff, l4swz);
    asm volatile("s_waitcnt vmcnt(0)" ::: "memory");   // drains A half1
    __builtin_amdgcn_s_barrier();
    LGKM_SYNC();
    MFMA_QUAD(0, 1);
    __builtin_amdgcn_s_barrier();
    // p2: quad (1,1) — reads A half1 (drained above); no more LDS writes
    read_af(af, rb, 1, rowAoff, l4swz);
    LGKM_SYNC();
    MFMA_QUAD(1, 1);
    // p3: quad (1,0)
    read_bf(bfr, rb, 0, rowBoff, l4swz);
    LGKM_SYNC();
    MFMA_QUAD(1, 0);
  }

  // Epilogue: exp(cos*20 - 20), row-sum over this block's 256 cols.
  // C/D frag layout: col = l15, row-in-frag = l4*4 + r  [m89 verified]
  // acc[am][nb]: row = (am>>2)*128 + wr*64 + (am&3)*16 + l4*4 + r
  float* psum = (float*)lds;  // overlay buf0-A region (tile 7 read buf1)
  __builtin_amdgcn_s_barrier();   // all waves done reading buf0 before overlay
  #pragma unroll
  for (int am = 0; am < 8; ++am) {
    #pragma unroll
    for (int r = 0; r < 4; ++r) {
      float s = 0.0f;
      #pragma unroll
      for (int nb = 0; nb < 4; ++nb)
        s += __expf(acc[am][nb][r] * 20.0f - 20.0f);
      s += __shfl_xor(s, 1, 64);
      s += __shfl_xor(s, 2, 64);
      s += __shfl_xor(s, 4, 64);
      s += __shfl_xor(s, 8, 64);
      if (l15 == 0)
        psum[wc * 256 + (am >> 2) * 128 + wr * 64 + (am & 3) * 16 + l4 * 4 + r] = s;
    }
  }
  __syncthreads();
  if (tid < 256) {
    float s = psum[tid] + psum[256 + tid] + psum[512 + tid] + psum[768 + tid];
    partial[(size_t)(bm + tid) * 32 + bx] = s;
  }
}

// ---------- Phase 3a: per-row loss ----------
__global__ __launch_bounds__(256) void rowloss_k(
    const float* __restrict__ partial, const float* __restrict__ diag,
    float* __restrict__ rowloss) {
  const int i = blockIdx.x * 256 + threadIdx.x;
  const float4* pr = (const float4*)(partial + (size_t)i * 32);
  float s = 0.0f;
  #pragma unroll
  for (int c = 0; c < 8; ++c) {
    const float4 v = pr[c];
    s += v.x + v.y + v.z + v.w;
  }
  rowloss[i] = __logf(s) + 20.0f - diag[i];
}

// ---------- Phase 3b: mean ----------
__global__ __launch_bounds__(256) void final_k(
    const float* __restrict__ rowloss, float* __restrict__ out) {
  const int t = threadIdx.x;
  float s = 0.0f;
  for (int j = t; j < NROWS; j += 256) s += rowloss[j];
  #pragma unroll
  for (int m = 1; m < 64; m <<= 1) s += __shfl_xor(s, m, 64);
  __shared__ float red[4];
  if ((t & 63) == 0) red[t >> 6] = s;
  __syncthreads();
  if (t == 0) out[0] = (red[0] + red[1] + red[2] + red[3]) * (1.0f / (float)NROWS);
}

extern "C" void kernel_launch(void* const* d_in, const int* in_sizes, int n_in,
                              void* d_out, int out_size, void* d_ws, size_t ws_size,
                              hipStream_t stream) {
  const float* q = (const float*)d_in[0];
  const float* p = (const float*)d_in[1];
  char* w = (char*)d_ws;
  unsigned short* qh = (unsigned short*)w;                    // 8 MB
  unsigned short* ph = (unsigned short*)(w + 8388608);        // 8 MB
  float* partial    = (float*)(w + 16777216);                 // 1 MB [8192][32]
  float* diag       = (float*)(w + 17825792);                 // 32 KB
  float* rowloss    = (float*)(w + 17858560);                 // 32 KB
  float* out = (float*)d_out;

  prep_k<<<NROWS, 128, 0, stream>>>(q, p, qh, ph, diag);
  gemm_lse_k<<<1024, 512, 0, stream>>>(qh, ph, partial);
  rowloss_k<<<NROWS / 256, 256, 0, stream>>>(partial, diag, rowloss);
  final_k<<<1, 256, 0, stream>>>(rowloss, out);
}

// Round 6
// 102.691 us; speedup vs baseline: 1.3289x; 1.0359x over previous
//
#include <hip/hip_runtime.h>
#include <hip/hip_bf16.h>

#define NROWS 8192
#define DIM 512
#define BM 256
#define BN 256

typedef __bf16 bf16x8 __attribute__((ext_vector_type(8)));
typedef unsigned short u16x8 __attribute__((ext_vector_type(8)));
typedef float f32x4 __attribute__((ext_vector_type(4)));

__device__ __forceinline__ unsigned short f2bf(float f) {
  unsigned int u = __float_as_uint(f);
  u += 0x7fffu + ((u >> 16) & 1u);
  return (unsigned short)(u >> 16);
}

__device__ __forceinline__ void gld_lds16(const void* g, void* l) {
  __builtin_amdgcn_global_load_lds(
      (__attribute__((address_space(1))) unsigned int*)(g),
      (__attribute__((address_space(3))) unsigned int*)(l),
      16, 0, 0);
}

// ---------- Phase 1: normalize rows -> bf16; diag logits in fp32 ----------
__global__ __launch_bounds__(128) void prep_k(
    const float* __restrict__ q, const float* __restrict__ p,
    unsigned short* __restrict__ qh, unsigned short* __restrict__ ph,
    float* __restrict__ diag) {
  const int i = blockIdx.x;
  const int t = threadIdx.x;
  const int lane = t & 63, wid = t >> 6;
  const float4 qv = ((const float4*)(q + (size_t)i * DIM))[t];
  const float4 pv = ((const float4*)(p + (size_t)i * DIM))[t];
  float ssq = qv.x*qv.x + qv.y*qv.y + qv.z*qv.z + qv.w*qv.w;
  float ssp = pv.x*pv.x + pv.y*pv.y + pv.z*pv.z + pv.w*pv.w;
  float dt  = qv.x*pv.x + qv.y*pv.y + qv.z*pv.z + qv.w*pv.w;
  #pragma unroll
  for (int m = 1; m < 64; m <<= 1) {
    ssq += __shfl_xor(ssq, m, 64);
    ssp += __shfl_xor(ssp, m, 64);
    dt  += __shfl_xor(dt,  m, 64);
  }
  __shared__ float red[3][2];
  if (lane == 0) { red[0][wid] = ssq; red[1][wid] = ssp; red[2][wid] = dt; }
  __syncthreads();
  ssq = red[0][0] + red[0][1];
  ssp = red[1][0] + red[1][1];
  dt  = red[2][0] + red[2][1];
  const float invq = 1.0f / fmaxf(sqrtf(ssq), 1e-8f);
  const float invp = 1.0f / fmaxf(sqrtf(ssp), 1e-8f);
  ushort4 qo, po;
  qo.x = f2bf(qv.x * invq); qo.y = f2bf(qv.y * invq);
  qo.z = f2bf(qv.z * invq); qo.w = f2bf(qv.w * invq);
  po.x = f2bf(pv.x * invp); po.y = f2bf(pv.y * invp);
  po.z = f2bf(pv.z * invp); po.w = f2bf(pv.w * invp);
  ((ushort4*)(qh + (size_t)i * DIM))[t] = qo;
  ((ushort4*)(ph + (size_t)i * DIM))[t] = po;
  if (t == 0) diag[i] = dt * invq * invp * 20.0f;
}

// ---------- Phase 2: persistent 256-block GEMM, 3-barrier/K-tile ----------
// Grid 256 (1 block/CU). Each block: 4 tiles (same bm, XCD-grouped bn),
// flat 32-K-tile pipeline, epilogue flush overlapped with next tile's loads.
// Hazard proof (steady state, queue invariant 4 entering each tile):
//   p0: read A0,B0 (drained @ t-1 p3 vmcnt+bar); stage A0'; vmcnt(4)
//       [drains B1(t)]; bar; lgkm; MFMA(0,0)
//   p1: read B1 (drained @ p0);    stage B0'; vmcnt(4) [drains A1(t)]; bar;
//       lgkm; MFMA(0,1)
//   p2: read A1 (drained @ p1);    stage B1'; lgkm; MFMA(1,1)   [no barrier:
//       reads collectively drained @ p1; stage-target's old readers finished
//       their lgkm >=2 barriers ago]
//   p3: read B0 again;             stage A1'; vmcnt(4) [drains A0',B0']; bar;
//       lgkm; MFMA(1,0)
__device__ __forceinline__ void read_af(bf16x8 af[2][4], const char* rb,
                                        int qm, int rowAoff, int l4swz) {
  #pragma unroll
  for (int ks = 0; ks < 2; ++ks)
    #pragma unroll
    for (int mf = 0; mf < 4; ++mf)
      af[ks][mf] = __builtin_bit_cast(bf16x8,
          *(const u16x8*)(rb + qm * 16384 + rowAoff + mf * 2048 + (l4swz ^ (ks * 64))));
}
__device__ __forceinline__ void read_bf(bf16x8 bfr[2][2], const char* rb,
                                        int qn, int rowBoff, int l4swz) {
  #pragma unroll
  for (int ks = 0; ks < 2; ++ks)
    #pragma unroll
    for (int nf = 0; nf < 2; ++nf)
      bfr[ks][nf] = __builtin_bit_cast(bf16x8,
          *(const u16x8*)(rb + 32768 + qn * 16384 + rowBoff + nf * 2048 + (l4swz ^ (ks * 64))));
}
__device__ __forceinline__ void stage_half(const char* __restrict__ g, char* dstb,
                                           int rowbase, int h, int tid, int kb) {
  #pragma unroll
  for (int j = 0; j < 2; ++j) {
    const int idx = j * 512 + tid;
    const int rl = idx >> 3;
    const int scb = ((idx & 7) << 4) ^ ((rl & 7) << 4);
    gld_lds16(g + (size_t)(rowbase + h * 128 + rl) * 1024 + kb + scb,
              dstb + h * 16384 + idx * 16);
  }
}

#define MFMA_QUAD(QM, QN)                                                     \
  __builtin_amdgcn_s_setprio(1);                                              \
  _Pragma("unroll") for (int mf = 0; mf < 4; ++mf)                            \
    _Pragma("unroll") for (int nf = 0; nf < 2; ++nf)                          \
      _Pragma("unroll") for (int ks = 0; ks < 2; ++ks)                        \
        acc[QM * 4 + mf][QN * 2 + nf] =                                       \
            __builtin_amdgcn_mfma_f32_16x16x32_bf16(                          \
                af[ks][mf], bfr[ks][nf], acc[QM * 4 + mf][QN * 2 + nf], 0, 0, 0); \
  __builtin_amdgcn_s_setprio(0);

#define VM_BAR(N)                                                             \
  asm volatile("s_waitcnt vmcnt(" #N ")" ::: "memory");                       \
  __builtin_amdgcn_s_barrier();

#define LGKM_SYNC()                                                           \
  asm volatile("s_waitcnt lgkmcnt(0)" ::: "memory");                          \
  __builtin_amdgcn_sched_barrier(0);

__global__ __launch_bounds__(512, 2) void gemm_lse_k(
    const unsigned short* __restrict__ qh, const unsigned short* __restrict__ ph,
    float* __restrict__ partial) {
  __shared__ __attribute__((aligned(16))) char lds[135168];  // 2x64KB + 4KB psum
  const int tid = threadIdx.x;
  const int lane = tid & 63, wid = tid >> 6;
  const int wr = wid >> 2, wc = wid & 3;
  const int l15 = lane & 15, l4 = lane >> 4;
  const int rowAoff = (wr * 64 + l15) * 128;
  const int rowBoff = (wc * 32 + l15) * 128;
  const int l4swz = (l4 << 4) ^ ((l15 & 7) << 4);
  const int b = blockIdx.x;
  const int bxg = b & 7;            // XCD id -> B column group (1MB, L2-hot)
  const int by = b >> 3;            // 0..31
  const int bm = by * BM;
  const char* qh8 = (const char*)qh;
  const char* ph8 = (const char*)ph;
  float* psum = (float*)(lds + 131072);

  f32x4 acc[8][4] = {};
  bf16x8 af[2][4], bfr[2][2];

  // Prologue: stage tile 0 (tile idx 0), drain fully, barrier. Only one ever.
  {
    const int bn0 = bxg * 4 * BN;
    stage_half(qh8, lds, bm, 0, tid, 0);
    stage_half(ph8, lds + 32768, bn0, 0, tid, 0);
    stage_half(ph8, lds + 32768, bn0, 1, tid, 0);
    stage_half(qh8, lds, bm, 1, tid, 0);
    asm volatile("s_waitcnt vmcnt(0)" ::: "memory");
    __builtin_amdgcn_s_barrier();
  }

  #pragma unroll 1
  for (int tt = 0; tt < 31; ++tt) {
    const char* rb = lds + (tt & 1) * 65536;
    char* sbA = lds + ((tt + 1) & 1) * 65536;
    char* sbB = sbA + 32768;
    const int ttn = tt + 1;
    const int kbn = (ttn & 7) * 128;                 // next K-tile byte offset
    const int bnn = (bxg * 4 + (ttn >> 3)) * BN;     // next tile's bn
    // p0
    read_af(af, rb, 0, rowAoff, l4swz);
    read_bf(bfr, rb, 0, rowBoff, l4swz);
    stage_half(qh8, sbA, bm, 0, tid, kbn);
    VM_BAR(4);
    LGKM_SYNC();
    MFMA_QUAD(0, 0);
    // p1
    read_bf(bfr, rb, 1, rowBoff, l4swz);
    stage_half(ph8, sbB, bnn, 0, tid, kbn);
    VM_BAR(4);
    LGKM_SYNC();
    MFMA_QUAD(0, 1);
    // p2 (no barrier, no vmcnt)
    read_af(af, rb, 1, rowAoff, l4swz);
    stage_half(ph8, sbB, bnn, 1, tid, kbn);
    LGKM_SYNC();
    MFMA_QUAD(1, 1);
    // p3
    read_bf(bfr, rb, 0, rowBoff, l4swz);
    stage_half(qh8, sbA, bm, 1, tid, kbn);
    VM_BAR(4);
    LGKM_SYNC();
    MFMA_QUAD(1, 0);

    if ((tt & 7) == 7) {
      // ---- flush tile (tt>>3): overlaps next tile's in-flight staging ----
      const int bxc = bxg * 4 + (tt >> 3);
      #pragma unroll
      for (int am = 0; am < 8; ++am) {
        #pragma unroll
        for (int r = 0; r < 4; ++r) {
          float s = 0.0f;
          #pragma unroll
          for (int nb = 0; nb < 4; ++nb)
            s += __expf(acc[am][nb][r] * 20.0f - 20.0f);
          s += __shfl_xor(s, 1, 64);
          s += __shfl_xor(s, 2, 64);
          s += __shfl_xor(s, 4, 64);
          s += __shfl_xor(s, 8, 64);
          if (l15 == 0)
            psum[wc * 256 + (am >> 2) * 128 + wr * 64 + (am & 3) * 16 + l4 * 4 + r] = s;
        }
      }
      asm volatile("s_waitcnt lgkmcnt(0)" ::: "memory");
      __builtin_amdgcn_s_barrier();
      if (tid < 256) {
        float s = psum[tid] + psum[256 + tid] + psum[512 + tid] + psum[768 + tid];
        partial[(size_t)(bm + tid) * 32 + bxc] = s;
      }
      #pragma unroll
      for (int am = 0; am < 8; ++am)
        #pragma unroll
        for (int nb = 0; nb < 4; ++nb)
          acc[am][nb] = f32x4{0.0f, 0.0f, 0.0f, 0.0f};
    }
  }

  // ---- Peeled tt=31 (reads buf1, no staging): explicit counted drains ----
  {
    const char* rb = lds + 65536;
    read_af(af, rb, 0, rowAoff, l4swz);
    read_bf(bfr, rb, 0, rowBoff, l4swz);
    VM_BAR(2);                    // drains B1(31)
    LGKM_SYNC();
    MFMA_QUAD(0, 0);
    read_bf(bfr, rb, 1, rowBoff, l4swz);
    VM_BAR(0);                    // drains A1(31)
    LGKM_SYNC();
    MFMA_QUAD(0, 1);
    read_af(af, rb, 1, rowAoff, l4swz);
    LGKM_SYNC();
    MFMA_QUAD(1, 1);
    read_bf(bfr, rb, 0, rowBoff, l4swz);
    LGKM_SYNC();
    MFMA_QUAD(1, 0);
    // flush tile 3
    const int bxc = bxg * 4 + 3;
    #pragma unroll
    for (int am = 0; am < 8; ++am) {
      #pragma unroll
      for (int r = 0; r < 4; ++r) {
        float s = 0.0f;
        #pragma unroll
        for (int nb = 0; nb < 4; ++nb)
          s += __expf(acc[am][nb][r] * 20.0f - 20.0f);
        s += __shfl_xor(s, 1, 64);
        s += __shfl_xor(s, 2, 64);
        s += __shfl_xor(s, 4, 64);
        s += __shfl_xor(s, 8, 64);
        if (l15 == 0)
          psum[wc * 256 + (am >> 2) * 128 + wr * 64 + (am & 3) * 16 + l4 * 4 + r] = s;
      }
    }
    asm volatile("s_waitcnt lgkmcnt(0)" ::: "memory");
    __builtin_amdgcn_s_barrier();
    if (tid < 256) {
      float s = psum[tid] + psum[256 + tid] + psum[512 + tid] + psum[768 + tid];
      partial[(size_t)(bm + tid) * 32 + bxc] = s;
    }
  }
}

// ---------- Phase 3a: per-row loss ----------
__global__ __launch_bounds__(256) void rowloss_k(
    const float* __restrict__ partial, const float* __restrict__ diag,
    float* __restrict__ rowloss) {
  const int i = blockIdx.x * 256 + threadIdx.x;
  const float4* pr = (const float4*)(partial + (size_t)i * 32);
  float s = 0.0f;
  #pragma unroll
  for (int c = 0; c < 8; ++c) {
    const float4 v = pr[c];
    s += v.x + v.y + v.z + v.w;
  }
  rowloss[i] = __logf(s) + 20.0f - diag[i];
}

// ---------- Phase 3b: mean ----------
__global__ __launch_bounds__(1024) void final_k(
    const float* __restrict__ rowloss, float* __restrict__ out) {
  const int t = threadIdx.x;
  float s = 0.0f;
  #pragma unroll
  for (int j = 0; j < 8; ++j) s += rowloss[t + j * 1024];
  #pragma unroll
  for (int m = 1; m < 64; m <<= 1) s += __shfl_xor(s, m, 64);
  __shared__ float red[16];
  if ((t & 63) == 0) red[t >> 6] = s;
  __syncthreads();
  if (t == 0) {
    float acc = 0.0f;
    #pragma unroll
    for (int w = 0; w < 16; ++w) acc += red[w];
    out[0] = acc * (1.0f / (float)NROWS);
  }
}

extern "C" void kernel_launch(void* const* d_in, const int* in_sizes, int n_in,
                              void* d_out, int out_size, void* d_ws, size_t ws_size,
                              hipStream_t stream) {
  const float* q = (const float*)d_in[0];
  const float* p = (const float*)d_in[1];
  char* w = (char*)d_ws;
  unsigned short* qh = (unsigned short*)w;                    // 8 MB
  unsigned short* ph = (unsigned short*)(w + 8388608);        // 8 MB
  float* partial    = (float*)(w + 16777216);                 // 1 MB [8192][32]
  float* diag       = (float*)(w + 17825792);                 // 32 KB
  float* rowloss    = (float*)(w + 17858560);                 // 32 KB
  float* out = (float*)d_out;

  prep_k<<<NROWS, 128, 0, stream>>>(q, p, qh, ph, diag);
  gemm_lse_k<<<256, 512, 0, stream>>>(qh, ph, partial);
  rowloss_k<<<NROWS / 256, 256, 0, stream>>>(partial, diag, rowloss);
  final_k<<<1, 1024, 0, stream>>>(rowloss, out);
}

// Round 7
// 102.508 us; speedup vs baseline: 1.3313x; 1.0018x over previous
//
#include <hip/hip_runtime.h>
#include <hip/hip_bf16.h>

#define NROWS 8192
#define DIM 512
#define BM 256
#define BN 256

typedef __bf16 bf16x8 __attribute__((ext_vector_type(8)));
typedef unsigned short u16x8 __attribute__((ext_vector_type(8)));
typedef float f32x4 __attribute__((ext_vector_type(4)));

__device__ __forceinline__ unsigned short f2bf(float f) {
  unsigned int u = __float_as_uint(f);
  u += 0x7fffu + ((u >> 16) & 1u);
  return (unsigned short)(u >> 16);
}

__device__ __forceinline__ void gld_lds16(const void* g, void* l) {
  __builtin_amdgcn_global_load_lds(
      (__attribute__((address_space(1))) unsigned int*)(g),
      (__attribute__((address_space(3))) unsigned int*)(l),
      16, 0, 0);
}

// ---------- Phase 1: normalize rows -> bf16; diag logits in fp32 ----------
__global__ __launch_bounds__(128) void prep_k(
    const float* __restrict__ q, const float* __restrict__ p,
    unsigned short* __restrict__ qh, unsigned short* __restrict__ ph,
    float* __restrict__ diag) {
  const int i = blockIdx.x;
  const int t = threadIdx.x;
  const int lane = t & 63, wid = t >> 6;
  const float4 qv = ((const float4*)(q + (size_t)i * DIM))[t];
  const float4 pv = ((const float4*)(p + (size_t)i * DIM))[t];
  float ssq = qv.x*qv.x + qv.y*qv.y + qv.z*qv.z + qv.w*qv.w;
  float ssp = pv.x*pv.x + pv.y*pv.y + pv.z*pv.z + pv.w*pv.w;
  float dt  = qv.x*pv.x + qv.y*pv.y + qv.z*pv.z + qv.w*pv.w;
  #pragma unroll
  for (int m = 1; m < 64; m <<= 1) {
    ssq += __shfl_xor(ssq, m, 64);
    ssp += __shfl_xor(ssp, m, 64);
    dt  += __shfl_xor(dt,  m, 64);
  }
  __shared__ float red[3][2];
  if (lane == 0) { red[0][wid] = ssq; red[1][wid] = ssp; red[2][wid] = dt; }
  __syncthreads();
  ssq = red[0][0] + red[0][1];
  ssp = red[1][0] + red[1][1];
  dt  = red[2][0] + red[2][1];
  const float invq = 1.0f / fmaxf(sqrtf(ssq), 1e-8f);
  const float invp = 1.0f / fmaxf(sqrtf(ssp), 1e-8f);
  ushort4 qo, po;
  qo.x = f2bf(qv.x * invq); qo.y = f2bf(qv.y * invq);
  qo.z = f2bf(qv.z * invq); qo.w = f2bf(qv.w * invq);
  po.x = f2bf(pv.x * invp); po.y = f2bf(pv.y * invp);
  po.z = f2bf(pv.z * invp); po.w = f2bf(pv.w * invp);
  ((ushort4*)(qh + (size_t)i * DIM))[t] = qo;
  ((ushort4*)(ph + (size_t)i * DIM))[t] = po;
  if (t == 0) diag[i] = dt * invq * invp * 20.0f;
}

// ---------- Phase 2: persistent GEMM, barrier-free tile interior ----------
// 256 blocks (1/CU), 8 waves (2M x 4N), per-wave 128x64 out, 4 tiles/block.
// Per K-tile: all 24 ds_read_b128 front-loaded into regs (af0/af1/bf0/bf1);
// compiler emits counted lgkmcnt so Q00's MFMAs start after 12 reads while
// later reads are in flight -> LDS pipe (~2700cy) and MFMA pipe (~2483cy)
// overlap instead of alternating. ONE vmcnt(0)+barrier per tile; stages for
// t+1 issue ~2000cy before the drain so it's cheap. vmcnt queue is 0 at
// every boundary -> tail tile needs no peel.
__device__ __forceinline__ void read_af(bf16x8 af[2][4], const char* rb,
                                        int qm, int rowAoff, int l4swz) {
  #pragma unroll
  for (int ks = 0; ks < 2; ++ks)
    #pragma unroll
    for (int mf = 0; mf < 4; ++mf)
      af[ks][mf] = __builtin_bit_cast(bf16x8,
          *(const u16x8*)(rb + qm * 16384 + rowAoff + mf * 2048 + (l4swz ^ (ks * 64))));
}
__device__ __forceinline__ void read_bf(bf16x8 bfr[2][2], const char* rb,
                                        int qn, int rowBoff, int l4swz) {
  #pragma unroll
  for (int ks = 0; ks < 2; ++ks)
    #pragma unroll
    for (int nf = 0; nf < 2; ++nf)
      bfr[ks][nf] = __builtin_bit_cast(bf16x8,
          *(const u16x8*)(rb + 32768 + qn * 16384 + rowBoff + nf * 2048 + (l4swz ^ (ks * 64))));
}
__device__ __forceinline__ void stage_half(const char* __restrict__ g, char* dstb,
                                           int rowbase, int h, int tid, int kb) {
  #pragma unroll
  for (int j = 0; j < 2; ++j) {
    const int idx = j * 512 + tid;
    const int rl = idx >> 3;
    const int scb = ((idx & 7) << 4) ^ ((rl & 7) << 4);
    gld_lds16(g + (size_t)(rowbase + h * 128 + rl) * 1024 + kb + scb,
              dstb + h * 16384 + idx * 16);
  }
}

#define MFMA_Q(AF, BF, QM, QN)                                                \
  __builtin_amdgcn_s_setprio(1);                                              \
  _Pragma("unroll") for (int mf = 0; mf < 4; ++mf)                            \
    _Pragma("unroll") for (int nf = 0; nf < 2; ++nf)                          \
      _Pragma("unroll") for (int ks = 0; ks < 2; ++ks)                        \
        acc[QM * 4 + mf][QN * 2 + nf] =                                       \
            __builtin_amdgcn_mfma_f32_16x16x32_bf16(                          \
                AF[ks][mf], BF[ks][nf], acc[QM * 4 + mf][QN * 2 + nf], 0, 0, 0); \
  __builtin_amdgcn_s_setprio(0);

__global__ __launch_bounds__(512, 2) void gemm_lse_k(
    const unsigned short* __restrict__ qh, const unsigned short* __restrict__ ph,
    float* __restrict__ partial) {
  __shared__ __attribute__((aligned(16))) char lds[135168];  // 2x64KB + 4KB psum
  const int tid = threadIdx.x;
  const int lane = tid & 63, wid = tid >> 6;
  const int wr = wid >> 2, wc = wid & 3;
  const int l15 = lane & 15, l4 = lane >> 4;
  const int rowAoff = (wr * 64 + l15) * 128;
  const int rowBoff = (wc * 32 + l15) * 128;
  const int l4swz = (l4 << 4) ^ ((l15 & 7) << 4);
  const int b = blockIdx.x;
  const int bxg = b & 7;            // XCD id -> B column group
  const int by = b >> 3;            // 0..31
  const int bm = by * BM;
  const char* qh8 = (const char*)qh;
  const char* ph8 = (const char*)ph;
  float* psum = (float*)(lds + 131072);

  f32x4 acc[8][4] = {};
  bf16x8 af0[2][4], af1[2][4], bf0[2][2], bf1[2][2];

  // Prologue: stage tile 0, drain, barrier. Once per kernel.
  {
    const int bn0 = bxg * 4 * BN;
    stage_half(qh8, lds, bm, 0, tid, 0);
    stage_half(ph8, lds + 32768, bn0, 0, tid, 0);
    stage_half(ph8, lds + 32768, bn0, 1, tid, 0);
    stage_half(qh8, lds, bm, 1, tid, 0);
    asm volatile("s_waitcnt vmcnt(0)" ::: "memory");
    __builtin_amdgcn_s_barrier();
  }

  #pragma unroll 1
  for (int tt = 0; tt < 32; ++tt) {
    const char* rb = lds + (tt & 1) * 65536;
    char* sbA = lds + ((tt + 1) & 1) * 65536;
    char* sbB = sbA + 32768;
    const int ttn = tt + 1;
    const int kbn = (ttn & 7) * 128;                 // next K-tile byte offset
    const int bnn = (bxg * 4 + (ttn >> 3)) * BN;     // next tile's bn
    const bool st = (tt < 31);

    // front-load all reads for this tile (24 x ds_read_b128)
    read_af(af0, rb, 0, rowAoff, l4swz);
    read_bf(bf0, rb, 0, rowBoff, l4swz);
    read_bf(bf1, rb, 1, rowBoff, l4swz);
    if (st) {
      stage_half(qh8, sbA, bm, 0, tid, kbn);
      stage_half(ph8, sbB, bnn, 0, tid, kbn);
    }
    MFMA_Q(af0, bf0, 0, 0);          // waits lgkmcnt(12): af0+bf0 ready
    read_af(af1, rb, 1, rowAoff, l4swz);
    MFMA_Q(af0, bf1, 0, 1);          // bf1 ready; af1 in flight under Q00/Q01
    if (st) {
      stage_half(ph8, sbB, bnn, 1, tid, kbn);
      stage_half(qh8, sbA, bm, 1, tid, kbn);
    }
    MFMA_Q(af1, bf1, 1, 1);
    MFMA_Q(af1, bf0, 1, 0);

    asm volatile("s_waitcnt vmcnt(0)" ::: "memory");  // stages landed (issued early)
    __builtin_amdgcn_s_barrier();

    if ((tt & 7) == 7) {
      // ---- flush output tile (tt>>3): exp + row-sum + store ----
      const int bxc = bxg * 4 + (tt >> 3);
      #pragma unroll
      for (int am = 0; am < 8; ++am) {
        #pragma unroll
        for (int r = 0; r < 4; ++r) {
          float s = 0.0f;
          #pragma unroll
          for (int nb = 0; nb < 4; ++nb)
            s += __expf(acc[am][nb][r] * 20.0f - 20.0f);
          s += __shfl_xor(s, 1, 64);
          s += __shfl_xor(s, 2, 64);
          s += __shfl_xor(s, 4, 64);
          s += __shfl_xor(s, 8, 64);
          if (l15 == 0)
            psum[wc * 256 + (am >> 2) * 128 + wr * 64 + (am & 3) * 16 + l4 * 4 + r] = s;
        }
      }
      asm volatile("s_waitcnt lgkmcnt(0)" ::: "memory");
      __builtin_amdgcn_s_barrier();
      if (tid < 256) {
        float s = psum[tid] + psum[256 + tid] + psum[512 + tid] + psum[768 + tid];
        partial[(size_t)(bm + tid) * 32 + bxc] = s;
      }
      #pragma unroll
      for (int am = 0; am < 8; ++am)
        #pragma unroll
        for (int nb = 0; nb < 4; ++nb)
          acc[am][nb] = f32x4{0.0f, 0.0f, 0.0f, 0.0f};
    }
  }
}

// ---------- Phase 3a: per-row loss ----------
__global__ __launch_bounds__(256) void rowloss_k(
    const float* __restrict__ partial, const float* __restrict__ diag,
    float* __restrict__ rowloss) {
  const int i = blockIdx.x * 256 + threadIdx.x;
  const float4* pr = (const float4*)(partial + (size_t)i * 32);
  float s = 0.0f;
  #pragma unroll
  for (int c = 0; c < 8; ++c) {
    const float4 v = pr[c];
    s += v.x + v.y + v.z + v.w;
  }
  rowloss[i] = __logf(s) + 20.0f - diag[i];
}

// ---------- Phase 3b: mean ----------
__global__ __launch_bounds__(1024) void final_k(
    const float* __restrict__ rowloss, float* __restrict__ out) {
  const int t = threadIdx.x;
  float s = 0.0f;
  #pragma unroll
  for (int j = 0; j < 8; ++j) s += rowloss[t + j * 1024];
  #pragma unroll
  for (int m = 1; m < 64; m <<= 1) s += __shfl_xor(s, m, 64);
  __shared__ float red[16];
  if ((t & 63) == 0) red[t >> 6] = s;
  __syncthreads();
  if (t == 0) {
    float acc = 0.0f;
    #pragma unroll
    for (int w = 0; w < 16; ++w) acc += red[w];
    out[0] = acc * (1.0f / (float)NROWS);
  }
}

extern "C" void kernel_launch(void* const* d_in, const int* in_sizes, int n_in,
                              void* d_out, int out_size, void* d_ws, size_t ws_size,
                              hipStream_t stream) {
  const float* q = (const float*)d_in[0];
  const float* p = (const float*)d_in[1];
  char* w = (char*)d_ws;
  unsigned short* qh = (unsigned short*)w;                    // 8 MB
  unsigned short* ph = (unsigned short*)(w + 8388608);        // 8 MB
  float* partial    = (float*)(w + 16777216);                 // 1 MB [8192][32]
  float* diag       = (float*)(w + 17825792);                 // 32 KB
  float* rowloss    = (float*)(w + 17858560);                 // 32 KB
  float* out = (float*)d_out;

  prep_k<<<NROWS, 128, 0, stream>>>(q, p, qh, ph, diag);
  gemm_lse_k<<<256, 512, 0, stream>>>(qh, ph, partial);
  rowloss_k<<<NROWS / 256, 256, 0, stream>>>(partial, diag, rowloss);
  final_k<<<1, 1024, 0, stream>>>(rowloss, out);
}